// Round 13
// baseline (331.761 us; speedup 1.0000x reference)
//
#include <hip/hip_runtime.h>

#define N_NODES 50000
#define N_EDGES 800000
#define DIM 128
#define N_REL 86
#define BATCH 2048

#define TPAD 136              // 128+8 bf16: 272 B row stride -> 2-way bank alias (free)
#define QPAD 136

#define G_CNT1 3125           // 800000 / 256, 1 edge/thread (exact)
#define G_GEMM 391            // ceil(50000/128)
#define G_TQ   172            // 86 relations x 2 d-blocks
#define NB_SCAN 49            // ceil(50000/1024)

using bf16x8 = __attribute__((ext_vector_type(8))) short;
using f32x4  = __attribute__((ext_vector_type(4))) float;

static __device__ __forceinline__ unsigned short f2bf(float f) {
  union { float f; unsigned int i; } v; v.f = f;
  unsigned int x = v.i;
  unsigned int r = x + 0x7FFFu + ((x >> 16) & 1u);
  return (unsigned short)(r >> 16);
}
static __device__ __forceinline__ float bf2f(unsigned short u) {
  union { unsigned int i; float f; } v;
  v.i = ((unsigned int)u) << 16;
  return v.f;
}

// ---------------- kernel 0: zero cnt + flags + weight prep ----------------
// flags[0] = arrival counter; flags[8..8+NB_SCAN) = block partials

__global__ __launch_bounds__(256) void k_prep_zero(const float* __restrict__ W1, const float* __restrict__ W2,
                                                   const float* __restrict__ M,
                                                   unsigned short* __restrict__ W1th, unsigned short* __restrict__ W1tl,
                                                   unsigned short* __restrict__ W2th, unsigned short* __restrict__ W2tl,
                                                   unsigned short* __restrict__ Mth,
                                                   int* __restrict__ cnt, int* __restrict__ flags) {
  int g = blockIdx.x * 256 + threadIdx.x;          // 65536 threads
  if (g < N_NODES) cnt[g] = 0;
  if (g < 64) flags[g] = 0;
  if (g < DIM * DIM) {
    int k = g >> 7, n = g & 127;
    int t = n * DIM + k;
    float w1 = W1[g]; unsigned short h1 = f2bf(w1);
    W1th[t] = h1; W1tl[t] = f2bf(w1 - bf2f(h1));
    float w2 = W2[g]; unsigned short h2 = f2bf(w2);
    W2th[t] = h2; W2tl[t] = f2bf(w2 - bf2f(h2));
    Mth[t] = f2bf(M[g]);
  }
}

// ---------------- megaA: edge count (+epos, 1/thread)  ||  decoder TQ ----------------

__global__ __launch_bounds__(256) void k_megaA(const int* __restrict__ dst,
                                               int* __restrict__ cnt, int* __restrict__ epos,
                                               const float* __restrict__ Rel,
                                               const unsigned short* __restrict__ Mth,
                                               unsigned short* __restrict__ Qbf) {
  __shared__ __align__(16) unsigned short Ts[64 * TPAD];
  int bid = blockIdx.x;
  int wave = threadIdx.x >> 6, lane = threadIdx.x & 63;
  int l15 = lane & 15, quad = lane >> 4;
  union U { uint4 u; bf16x8 h; };

  if (bid < G_CNT1) {
    int i = bid * 256 + threadIdx.x;   // exact: 3125*256 == 800000
    int d = dst[i];
    epos[i] = atomicAdd(&cnt[d], 1);
  } else {
    // ---- decoder precompute: T_r = Rel_r @ M (LDS), Q_r = T_r @ Rel_r^T ----
    int rb = bid - G_CNT1;
    int r = rb >> 1, dblk = rb & 1;
    const float* Rr = Rel + (size_t)r * DIM * DIM;
    unsigned short* Qr = Qbf + (size_t)r * DIM * DIM;
    int dw = dblk * 64 + wave * 16;
    f32x4 acc[8];
    #pragma unroll
    for (int nt = 0; nt < 8; ++nt) acc[nt] = f32x4{0.f, 0.f, 0.f, 0.f};
    #pragma unroll
    for (int ks = 0; ks < 4; ++ks) {
      int k0 = ks * 32 + quad * 8;
      const float* ap = Rr + (size_t)(dw + l15) * DIM + k0;
      float av[8];
      *(float4*)(av)     = *(const float4*)(ap);
      *(float4*)(av + 4) = *(const float4*)(ap + 4);
      bf16x8 a;
      #pragma unroll
      for (int j = 0; j < 8; ++j) a[j] = (short)f2bf(av[j]);
      #pragma unroll
      for (int nt = 0; nt < 8; ++nt) {
        U b; b.u = *(const uint4*)(Mth + (nt * 16 + l15) * DIM + k0);
        acc[nt] = __builtin_amdgcn_mfma_f32_16x16x32_bf16(a, b.h, acc[nt], 0, 0, 0);
      }
    }
    #pragma unroll
    for (int nt = 0; nt < 8; ++nt)
      #pragma unroll
      for (int reg = 0; reg < 4; ++reg)
        Ts[(wave * 16 + quad * 4 + reg) * TPAD + nt * 16 + l15] = f2bf(acc[nt][reg]);
    __syncthreads();
    f32x4 qacc[8];
    #pragma unroll
    for (int nt = 0; nt < 8; ++nt) qacc[nt] = f32x4{0.f, 0.f, 0.f, 0.f};
    #pragma unroll
    for (int ks = 0; ks < 4; ++ks) {
      int k0 = ks * 32 + quad * 8;
      U a; a.u = *(const uint4*)(&Ts[(wave * 16 + l15) * TPAD + k0]);
      #pragma unroll
      for (int nt = 0; nt < 8; ++nt) {
        const float* bp = Rr + (size_t)(nt * 16 + l15) * DIM + k0;
        float bv[8];
        *(float4*)(bv)     = *(const float4*)(bp);
        *(float4*)(bv + 4) = *(const float4*)(bp + 4);
        bf16x8 b;
        #pragma unroll
        for (int j = 0; j < 8; ++j) b[j] = (short)f2bf(bv[j]);
        qacc[nt] = __builtin_amdgcn_mfma_f32_16x16x32_bf16(a.h, b, qacc[nt], 0, 0, 0);
      }
    }
    #pragma unroll
    for (int nt = 0; nt < 8; ++nt)
      #pragma unroll
      for (int reg = 0; reg < 4; ++reg)
        Qr[(size_t)(dw + quad * 4 + reg) * DIM + nt * 16 + l15] = f2bf(qacc[nt][reg]);
  }
}

// ---------------- single-dispatch all-wait scan: dinv + rowptr ----------------
// 49 blocks (all co-resident). Each publishes its partial + bumps arrival counter;
// all blocks wait for the single convergence point, then read all partials in parallel.

__global__ __launch_bounds__(256) void k_scan_aw(const int* __restrict__ cnt, float* __restrict__ dinv,
                                                 int* __restrict__ rowptr, int* __restrict__ flags) {
  __shared__ int sd[256];
  __shared__ int s_prefix;
  int b = blockIdx.x;
  int base = b * 1024;
  int t = threadIdx.x;
  int v[4]; int s = 0;
  #pragma unroll
  for (int i = 0; i < 4; ++i) {
    int idx = base + t * 4 + i;
    if (idx < N_NODES) {
      int c = cnt[idx];
      v[i] = c;
      dinv[idx] = rsqrtf((float)(c + 1));
    } else v[i] = 0;
    s += v[i];
  }
  sd[t] = s; __syncthreads();
  for (int off = 1; off < 256; off <<= 1) {
    int y = (t >= off) ? sd[t - off] : 0;
    __syncthreads();
    sd[t] += y;
    __syncthreads();
  }
  int local_excl = sd[t] - s;
  int total = sd[255];
  if (t == 0) {
    atomicExch(&flags[8 + b], total);
    __threadfence();
    atomicAdd(&flags[0], 1);
    while (atomicAdd(&flags[0], 0) < NB_SCAN) { }
  }
  __syncthreads();
  // wave 0: parallel read of all partials; prefix = sum of partials with index < b
  if (t < 64) {
    int part = (t < NB_SCAN) ? atomicAdd(&flags[8 + t], 0) : 0;
    int pre = (t < b) ? part : 0;
    int tot = part;
    #pragma unroll
    for (int off = 32; off > 0; off >>= 1) {
      pre += __shfl_xor(pre, off, 64);
      tot += __shfl_xor(tot, off, 64);
    }
    if (t == 0) {
      s_prefix = pre;
      if (b == NB_SCAN - 1) rowptr[N_NODES] = tot;
    }
  }
  __syncthreads();
  int pre = s_prefix + local_excl;
  #pragma unroll
  for (int i = 0; i < 4; ++i) {
    int idx = base + t * 4 + i;
    if (idx < N_NODES) rowptr[idx] = pre;
    pre += v[i];
  }
}

// ---------------- megaB: CSR fill (no atomics, 1/thread)  ||  gemm1 ----------------

__global__ __launch_bounds__(256) void k_megaB(const int* __restrict__ src, const int* __restrict__ dst,
                                               const int* __restrict__ rowptr, const int* __restrict__ epos,
                                               int* __restrict__ esrc,
                                               const float* __restrict__ x,
                                               const unsigned short* __restrict__ W1th,
                                               const unsigned short* __restrict__ W1tl,
                                               unsigned short* __restrict__ hout) {
  int bid = blockIdx.x;
  union U { uint4 u; bf16x8 h; };
  if (bid < G_CNT1) {
    int i = bid * 256 + threadIdx.x;
    esrc[rowptr[dst[i]] + epos[i]] = src[i];
  } else {
    // ---- node GEMM layer 1: hout = x @ W1 (hi/lo 3-term, bf16 out) ----
    int wave = threadIdx.x >> 6, lane = threadIdx.x & 63;
    int l15 = lane & 15, quad = lane >> 4;
    int r0 = (bid - G_CNT1) * 128 + wave * 32;
    f32x4 acc[2][8];
    #pragma unroll
    for (int mt = 0; mt < 2; ++mt)
      #pragma unroll
      for (int nt = 0; nt < 8; ++nt) acc[mt][nt] = f32x4{0.f, 0.f, 0.f, 0.f};
    #pragma unroll
    for (int ks = 0; ks < 4; ++ks) {
      int k0 = ks * 32 + quad * 8;
      bf16x8 ah[2], al[2];
      #pragma unroll
      for (int mt = 0; mt < 2; ++mt) {
        int row = r0 + mt * 16 + l15;
        row = (row < N_NODES) ? row : (N_NODES - 1);
        const float* xp = x + (size_t)row * DIM + k0;
        float xv[8];
        *(float4*)(xv)     = *(const float4*)(xp);
        *(float4*)(xv + 4) = *(const float4*)(xp + 4);
        #pragma unroll
        for (int j = 0; j < 8; ++j) {
          unsigned short h = f2bf(xv[j]);
          ah[mt][j] = (short)h;
          al[mt][j] = (short)f2bf(xv[j] - bf2f(h));
        }
      }
      #pragma unroll
      for (int nt = 0; nt < 8; ++nt) {
        U bh, bl;
        bh.u = *(const uint4*)(W1th + (nt * 16 + l15) * DIM + k0);
        bl.u = *(const uint4*)(W1tl + (nt * 16 + l15) * DIM + k0);
        #pragma unroll
        for (int mt = 0; mt < 2; ++mt) {
          acc[mt][nt] = __builtin_amdgcn_mfma_f32_16x16x32_bf16(ah[mt], bh.h, acc[mt][nt], 0, 0, 0);
          acc[mt][nt] = __builtin_amdgcn_mfma_f32_16x16x32_bf16(al[mt], bh.h, acc[mt][nt], 0, 0, 0);
          acc[mt][nt] = __builtin_amdgcn_mfma_f32_16x16x32_bf16(ah[mt], bl.h, acc[mt][nt], 0, 0, 0);
        }
      }
    }
    #pragma unroll
    for (int mt = 0; mt < 2; ++mt)
      #pragma unroll
      for (int reg = 0; reg < 4; ++reg) {
        int row = r0 + mt * 16 + quad * 4 + reg;
        if (row < N_NODES) {
          #pragma unroll
          for (int nt = 0; nt < 8; ++nt)
            hout[(size_t)row * DIM + nt * 16 + l15] = f2bf(acc[mt][nt][reg]);
        }
      }
  }
}

// ---------------- agg: bf16 plane in -> hi/lo bf16 planes out ----------------

__global__ __launch_bounds__(256) void k_agg_hl(const unsigned short* __restrict__ h,
                                                const int* __restrict__ rowptr,
                                                const int* __restrict__ esrc, const float* __restrict__ dinv,
                                                const float* __restrict__ bias,
                                                unsigned short* __restrict__ outh,
                                                unsigned short* __restrict__ outl) {
  int node = blockIdx.x * 8 + (threadIdx.x >> 5);
  if (node >= N_NODES) return;
  int lane = threadIdx.x & 31;
  const ushort4* h4 = (const ushort4*)h;
  float di = dinv[node];
  ushort4 hv = h4[(size_t)node * 32 + lane];
  float ax = di * bf2f(hv.x), ay = di * bf2f(hv.y), az = di * bf2f(hv.z), aw = di * bf2f(hv.w);
  int e = rowptr[node], end = rowptr[node + 1];
  for (; e + 3 < end; e += 4) {
    int s0 = esrc[e], s1 = esrc[e + 1], s2 = esrc[e + 2], s3 = esrc[e + 3];
    float d0 = dinv[s0], d1 = dinv[s1], d2 = dinv[s2], d3 = dinv[s3];
    ushort4 v0 = h4[(size_t)s0 * 32 + lane];
    ushort4 v1 = h4[(size_t)s1 * 32 + lane];
    ushort4 v2 = h4[(size_t)s2 * 32 + lane];
    ushort4 v3 = h4[(size_t)s3 * 32 + lane];
    ax = fmaf(d0, bf2f(v0.x), ax); ay = fmaf(d0, bf2f(v0.y), ay); az = fmaf(d0, bf2f(v0.z), az); aw = fmaf(d0, bf2f(v0.w), aw);
    ax = fmaf(d1, bf2f(v1.x), ax); ay = fmaf(d1, bf2f(v1.y), ay); az = fmaf(d1, bf2f(v1.z), az); aw = fmaf(d1, bf2f(v1.w), aw);
    ax = fmaf(d2, bf2f(v2.x), ax); ay = fmaf(d2, bf2f(v2.y), ay); az = fmaf(d2, bf2f(v2.z), az); aw = fmaf(d2, bf2f(v2.w), aw);
    ax = fmaf(d3, bf2f(v3.x), ax); ay = fmaf(d3, bf2f(v3.y), ay); az = fmaf(d3, bf2f(v3.z), az); aw = fmaf(d3, bf2f(v3.w), aw);
  }
  for (; e < end; ++e) {
    int s = esrc[e];
    float ds = dinv[s];
    ushort4 vs = h4[(size_t)s * 32 + lane];
    ax = fmaf(ds, bf2f(vs.x), ax); ay = fmaf(ds, bf2f(vs.y), ay);
    az = fmaf(ds, bf2f(vs.z), az); aw = fmaf(ds, bf2f(vs.w), aw);
  }
  float4 bb = ((const float4*)bias)[lane];
  float vx = fmaf(di, ax, bb.x), vy = fmaf(di, ay, bb.y);
  float vz = fmaf(di, az, bb.z), vw = fmaf(di, aw, bb.w);
  ushort4 hi4, lo4;
  hi4.x = f2bf(vx); lo4.x = f2bf(vx - bf2f(hi4.x));
  hi4.y = f2bf(vy); lo4.y = f2bf(vy - bf2f(hi4.y));
  hi4.z = f2bf(vz); lo4.z = f2bf(vz - bf2f(hi4.z));
  hi4.w = f2bf(vw); lo4.w = f2bf(vw - bf2f(hi4.w));
  ((ushort4*)outh)[(size_t)node * 32 + lane] = hi4;
  ((ushort4*)outl)[(size_t)node * 32 + lane] = lo4;
}

// ---------------- gemm2: A from hi/lo planes, 3-term, bf16 out ----------------

__global__ __launch_bounds__(256) void k_gemm_hl(const unsigned short* __restrict__ xh,
                                                 const unsigned short* __restrict__ xl,
                                                 const unsigned short* __restrict__ Wth,
                                                 const unsigned short* __restrict__ Wtl,
                                                 unsigned short* __restrict__ out, int nrows) {
  int wave = threadIdx.x >> 6, lane = threadIdx.x & 63;
  int l15 = lane & 15, quad = lane >> 4;
  int r0 = blockIdx.x * 128 + wave * 32;
  f32x4 acc[2][8];
  #pragma unroll
  for (int mt = 0; mt < 2; ++mt)
    #pragma unroll
    for (int nt = 0; nt < 8; ++nt) acc[mt][nt] = f32x4{0.f, 0.f, 0.f, 0.f};
  union U { uint4 u; bf16x8 h; };
  #pragma unroll
  for (int ks = 0; ks < 4; ++ks) {
    int k0 = ks * 32 + quad * 8;
    U ah[2], al[2];
    #pragma unroll
    for (int mt = 0; mt < 2; ++mt) {
      int row = r0 + mt * 16 + l15;
      row = (row < nrows) ? row : (nrows - 1);
      ah[mt].u = *(const uint4*)(xh + (size_t)row * DIM + k0);
      al[mt].u = *(const uint4*)(xl + (size_t)row * DIM + k0);
    }
    #pragma unroll
    for (int nt = 0; nt < 8; ++nt) {
      U bh, bl;
      bh.u = *(const uint4*)(Wth + (nt * 16 + l15) * DIM + k0);
      bl.u = *(const uint4*)(Wtl + (nt * 16 + l15) * DIM + k0);
      #pragma unroll
      for (int mt = 0; mt < 2; ++mt) {
        acc[mt][nt] = __builtin_amdgcn_mfma_f32_16x16x32_bf16(ah[mt].h, bh.h, acc[mt][nt], 0, 0, 0);
        acc[mt][nt] = __builtin_amdgcn_mfma_f32_16x16x32_bf16(al[mt].h, bh.h, acc[mt][nt], 0, 0, 0);
        acc[mt][nt] = __builtin_amdgcn_mfma_f32_16x16x32_bf16(ah[mt].h, bl.h, acc[mt][nt], 0, 0, 0);
      }
    }
  }
  #pragma unroll
  for (int mt = 0; mt < 2; ++mt)
    #pragma unroll
    for (int reg = 0; reg < 4; ++reg) {
      int row = r0 + mt * 16 + quad * 4 + reg;
      if (row < nrows) {
        #pragma unroll
        for (int nt = 0; nt < 8; ++nt)
          out[(size_t)row * DIM + nt * 16 + l15] = f2bf(acc[mt][nt][reg]);
      }
    }
}

// ---------------- predict via MFMA: 4 batch-tiles per Q-load ----------------

__global__ __launch_bounds__(256) void k_predict_mfma(const unsigned short* __restrict__ xh,
                                                      const unsigned short* __restrict__ xl,
                                                      const int* __restrict__ head,
                                                      const int* __restrict__ tail,
                                                      const unsigned short* __restrict__ Qbf,
                                                      float* __restrict__ out) {
  __shared__ __align__(16) unsigned short Qs[DIM * QPAD];
  __shared__ int Hidx[128];
  __shared__ int Tidx[128];
  int r = blockIdx.y;
  const unsigned short* Qr = Qbf + (size_t)r * DIM * DIM;
  for (int i = threadIdx.x; i < DIM * DIM / 8; i += 256) {
    int d = i >> 4, c = (i & 15) * 8;
    uint4 v = ((const uint4*)Qr)[i];
    *(uint4*)(&Qs[d * QPAD + c]) = v;
  }
  int wave = threadIdx.x >> 6, lane = threadIdx.x & 63;
  int l15 = lane & 15, quad = lane >> 4;
  union U { uint4 u; bf16x8 h; };

  for (int k = 0; k < 4; ++k) {
    int tile = blockIdx.x * 4 + k;
    __syncthreads();  // protect Hidx/Tidx (and on k==0, Qs) from previous readers
    if (threadIdx.x < 128) Hidx[threadIdx.x] = head[tile * 128 + threadIdx.x];
    else Tidx[threadIdx.x - 128] = tail[tile * 128 + threadIdx.x - 128];
    __syncthreads();
    int t0r = Tidx[wave * 32 + l15];
    int t1r = Tidx[wave * 32 + 16 + l15];

    f32x4 acc[2][8];
    #pragma unroll
    for (int m = 0; m < 2; ++m)
      #pragma unroll
      for (int n = 0; n < 8; ++n) acc[m][n] = f32x4{0.f, 0.f, 0.f, 0.f};

    #pragma unroll
    for (int ks = 0; ks < 4; ++ks) {
      int eoff = ks * 32 + quad * 8;
      U a0, a1;
      a0.u = *(const uint4*)(xh + (size_t)t0r * DIM + eoff);   // tail = hi plane
      a1.u = *(const uint4*)(xh + (size_t)t1r * DIM + eoff);
      #pragma unroll
      for (int nt = 0; nt < 8; ++nt) {
        U b; b.u = *(const uint4*)(&Qs[(nt * 16 + l15) * QPAD + eoff]);
        acc[0][nt] = __builtin_amdgcn_mfma_f32_16x16x32_bf16(a0.h, b.h, acc[0][nt], 0, 0, 0);
        acc[1][nt] = __builtin_amdgcn_mfma_f32_16x16x32_bf16(a1.h, b.h, acc[1][nt], 0, 0, 0);
      }
    }

    int bbase = tile * 128 + wave * 32;
    #pragma unroll
    for (int m = 0; m < 2; ++m) {
      #pragma unroll
      for (int reg = 0; reg < 4; ++reg) {
        int bl = wave * 32 + m * 16 + quad * 4 + reg;
        int hrow = Hidx[bl];
        float s = 0.f;
        #pragma unroll
        for (int nt = 0; nt < 8; ++nt) {
          size_t idx = (size_t)hrow * DIM + nt * 16 + l15;
          s += (bf2f(xh[idx]) + bf2f(xl[idx])) * acc[m][nt][reg];  // head = hi+lo
        }
        #pragma unroll
        for (int off = 1; off < 16; off <<= 1) s += __shfl_xor(s, off, 64);
        if (l15 == 0) out[(size_t)(bbase + m * 16 + quad * 4 + reg) * N_REL + r] = s;
      }
    }
  }
}

// ---------------- launch ----------------

extern "C" void kernel_launch(void* const* d_in, const int* in_sizes, int n_in,
                              void* d_out, int out_size, void* d_ws, size_t ws_size,
                              hipStream_t stream) {
  (void)in_sizes; (void)n_in; (void)out_size; (void)ws_size;
  const float* init_emb = (const float*)d_in[0];
  const float* W1  = (const float*)d_in[1];
  const float* b1  = (const float*)d_in[2];
  const float* W2  = (const float*)d_in[3];
  const float* b2  = (const float*)d_in[4];
  const float* Rel = (const float*)d_in[5];
  const float* M   = (const float*)d_in[6];
  const int* head  = (const int*)d_in[7];
  const int* tail  = (const int*)d_in[8];
  const int* src   = (const int*)d_in[9];
  const int* dst   = src + N_EDGES;
  float* out = (float*)d_out;

  char* p = (char*)d_ws;
  auto alloc = [&](size_t bytes) { char* q = p; p += (bytes + 511) & ~(size_t)511; return q; };
  int*   cnt    = (int*)alloc((size_t)N_NODES * 4);
  int*   rowptr = (int*)alloc((size_t)(N_NODES + 1) * 4);
  int*   flags  = (int*)alloc(64 * 4);
  int*   esrc   = (int*)alloc((size_t)N_EDGES * 4);
  int*   epos   = (int*)alloc((size_t)N_EDGES * 4);
  float* dinv   = (float*)alloc((size_t)N_NODES * 4);
  unsigned short* hbuf1 = (unsigned short*)alloc((size_t)N_NODES * DIM * 2);
  unsigned short* aggh  = (unsigned short*)alloc((size_t)N_NODES * DIM * 2);
  unsigned short* aggl  = (unsigned short*)alloc((size_t)N_NODES * DIM * 2);
  unsigned short* hbuf2 = (unsigned short*)alloc((size_t)N_NODES * DIM * 2);
  unsigned short* xh    = (unsigned short*)alloc((size_t)N_NODES * DIM * 2);
  unsigned short* xl    = (unsigned short*)alloc((size_t)N_NODES * DIM * 2);
  unsigned short* Qbf   = (unsigned short*)alloc((size_t)N_REL * DIM * DIM * 2);
  unsigned short* W1th  = (unsigned short*)alloc((size_t)DIM * DIM * 2);
  unsigned short* W1tl  = (unsigned short*)alloc((size_t)DIM * DIM * 2);
  unsigned short* W2th  = (unsigned short*)alloc((size_t)DIM * DIM * 2);
  unsigned short* W2tl  = (unsigned short*)alloc((size_t)DIM * DIM * 2);
  unsigned short* Mth   = (unsigned short*)alloc((size_t)DIM * DIM * 2);

  // 1: zero cnt/flags + weight prep
  k_prep_zero<<<256, 256, 0, stream>>>(W1, W2, M, W1th, W1tl, W2th, W2tl, Mth, cnt, flags);
  // 2: count(+epos, 1/thr) || decoder TQ
  k_megaA<<<G_CNT1 + G_TQ, 256, 0, stream>>>(dst, cnt, epos, Rel, Mth, Qbf);
  // 3: single-dispatch all-wait scan (dinv + rowptr)
  k_scan_aw<<<NB_SCAN, 256, 0, stream>>>(cnt, dinv, rowptr, flags);
  // 4: fill (no atomics, 1/thr) || gemm1
  k_megaB<<<G_CNT1 + G_GEMM, 256, 0, stream>>>(src, dst, rowptr, epos, esrc,
                                               init_emb, W1th, W1tl, hbuf1);
  // 5: agg1 -> hi/lo planes
  k_agg_hl<<<(N_NODES + 7) / 8, 256, 0, stream>>>(hbuf1, rowptr, esrc, dinv, b1, aggh, aggl);
  // 6: gemm2 from planes
  k_gemm_hl<<<(N_NODES + 127) / 128, 256, 0, stream>>>(aggh, aggl, W2th, W2tl, hbuf2, N_NODES);
  // 7: agg2 -> hi/lo planes
  k_agg_hl<<<(N_NODES + 7) / 8, 256, 0, stream>>>(hbuf2, rowptr, esrc, dinv, b2, xh, xl);
  // 8: predict (4 tiles per Q-load)
  k_predict_mfma<<<dim3(4, N_REL), 256, 0, stream>>>(xh, xl, head, tail, Qbf, out);
}

// Round 14
// 297.108 us; speedup vs baseline: 1.1166x; 1.1166x over previous
//
#include <hip/hip_runtime.h>

#define N_NODES 50000
#define N_EDGES 800000
#define DIM 128
#define N_REL 86
#define BATCH 2048

#define TPAD 136              // 128+8 bf16: 272 B row stride -> 2-way bank alias (free)
#define QPAD 136

#define G_EDGE4 782           // ceil(800000/1024), 4 edges/thread (best-measured: 50 us)
#define G_GEMM 391            // ceil(50000/128)
#define G_TQ   172            // 86 relations x 2 d-blocks
#define NB_SCAN 49            // ceil(50000/1024)

using bf16x8 = __attribute__((ext_vector_type(8))) short;
using f32x4  = __attribute__((ext_vector_type(4))) float;

static __device__ __forceinline__ unsigned short f2bf(float f) {
  union { float f; unsigned int i; } v; v.f = f;
  unsigned int x = v.i;
  unsigned int r = x + 0x7FFFu + ((x >> 16) & 1u);
  return (unsigned short)(r >> 16);
}
static __device__ __forceinline__ float bf2f(unsigned short u) {
  union { unsigned int i; float f; } v;
  v.i = ((unsigned int)u) << 16;
  return v.f;
}

// ---------------- kernel 0: zero cnt + flags + weight prep ----------------
// flags[0] = arrival counter; flags[8..8+NB_SCAN) = block partials

__global__ __launch_bounds__(256) void k_prep_zero(const float* __restrict__ W1, const float* __restrict__ W2,
                                                   const float* __restrict__ M,
                                                   unsigned short* __restrict__ W1th, unsigned short* __restrict__ W1tl,
                                                   unsigned short* __restrict__ W2th, unsigned short* __restrict__ W2tl,
                                                   unsigned short* __restrict__ Mth,
                                                   int* __restrict__ cnt, int* __restrict__ flags) {
  int g = blockIdx.x * 256 + threadIdx.x;          // 65536 threads
  if (g < N_NODES) cnt[g] = 0;
  if (g < 64) flags[g] = 0;
  if (g < DIM * DIM) {
    int k = g >> 7, n = g & 127;
    int t = n * DIM + k;
    float w1 = W1[g]; unsigned short h1 = f2bf(w1);
    W1th[t] = h1; W1tl[t] = f2bf(w1 - bf2f(h1));
    float w2 = W2[g]; unsigned short h2 = f2bf(w2);
    W2th[t] = h2; W2tl[t] = f2bf(w2 - bf2f(h2));
    Mth[t] = f2bf(M[g]);
  }
}

// ---------------- megaA: edge count (+epos, 4/thread)  ||  decoder TQ ----------------

__global__ __launch_bounds__(256) void k_megaA(const int* __restrict__ dst,
                                               int* __restrict__ cnt, int* __restrict__ epos,
                                               const float* __restrict__ Rel,
                                               const unsigned short* __restrict__ Mth,
                                               unsigned short* __restrict__ Qbf) {
  __shared__ __align__(16) unsigned short Ts[64 * TPAD];
  int bid = blockIdx.x;
  int wave = threadIdx.x >> 6, lane = threadIdx.x & 63;
  int l15 = lane & 15, quad = lane >> 4;
  union U { uint4 u; bf16x8 h; };

  if (bid < G_EDGE4) {
    int i0 = bid * 1024 + threadIdx.x * 4;
    if (i0 < N_EDGES) {
      int4 d4 = *(const int4*)(dst + i0);
      int4 e4;
      e4.x = atomicAdd(&cnt[d4.x], 1);
      e4.y = atomicAdd(&cnt[d4.y], 1);
      e4.z = atomicAdd(&cnt[d4.z], 1);
      e4.w = atomicAdd(&cnt[d4.w], 1);
      *(int4*)(epos + i0) = e4;
    }
  } else {
    // ---- decoder precompute: T_r = Rel_r @ M (LDS), Q_r = T_r @ Rel_r^T ----
    int rb = bid - G_EDGE4;
    int r = rb >> 1, dblk = rb & 1;
    const float* Rr = Rel + (size_t)r * DIM * DIM;
    unsigned short* Qr = Qbf + (size_t)r * DIM * DIM;
    int dw = dblk * 64 + wave * 16;
    f32x4 acc[8];
    #pragma unroll
    for (int nt = 0; nt < 8; ++nt) acc[nt] = f32x4{0.f, 0.f, 0.f, 0.f};
    #pragma unroll
    for (int ks = 0; ks < 4; ++ks) {
      int k0 = ks * 32 + quad * 8;
      const float* ap = Rr + (size_t)(dw + l15) * DIM + k0;
      float av[8];
      *(float4*)(av)     = *(const float4*)(ap);
      *(float4*)(av + 4) = *(const float4*)(ap + 4);
      bf16x8 a;
      #pragma unroll
      for (int j = 0; j < 8; ++j) a[j] = (short)f2bf(av[j]);
      #pragma unroll
      for (int nt = 0; nt < 8; ++nt) {
        U b; b.u = *(const uint4*)(Mth + (nt * 16 + l15) * DIM + k0);
        acc[nt] = __builtin_amdgcn_mfma_f32_16x16x32_bf16(a, b.h, acc[nt], 0, 0, 0);
      }
    }
    #pragma unroll
    for (int nt = 0; nt < 8; ++nt)
      #pragma unroll
      for (int reg = 0; reg < 4; ++reg)
        Ts[(wave * 16 + quad * 4 + reg) * TPAD + nt * 16 + l15] = f2bf(acc[nt][reg]);
    __syncthreads();
    f32x4 qacc[8];
    #pragma unroll
    for (int nt = 0; nt < 8; ++nt) qacc[nt] = f32x4{0.f, 0.f, 0.f, 0.f};
    #pragma unroll
    for (int ks = 0; ks < 4; ++ks) {
      int k0 = ks * 32 + quad * 8;
      U a; a.u = *(const uint4*)(&Ts[(wave * 16 + l15) * TPAD + k0]);
      #pragma unroll
      for (int nt = 0; nt < 8; ++nt) {
        const float* bp = Rr + (size_t)(nt * 16 + l15) * DIM + k0;
        float bv[8];
        *(float4*)(bv)     = *(const float4*)(bp);
        *(float4*)(bv + 4) = *(const float4*)(bp + 4);
        bf16x8 b;
        #pragma unroll
        for (int j = 0; j < 8; ++j) b[j] = (short)f2bf(bv[j]);
        qacc[nt] = __builtin_amdgcn_mfma_f32_16x16x32_bf16(a.h, b, qacc[nt], 0, 0, 0);
      }
    }
    #pragma unroll
    for (int nt = 0; nt < 8; ++nt)
      #pragma unroll
      for (int reg = 0; reg < 4; ++reg)
        Qr[(size_t)(dw + quad * 4 + reg) * DIM + nt * 16 + l15] = f2bf(qacc[nt][reg]);
  }
}

// ---------------- single-dispatch all-wait scan: dinv + rowptr ----------------
// 49 blocks (all co-resident). Each publishes its partial + bumps arrival counter;
// all blocks wait for the single convergence point, then read all partials in parallel.

__global__ __launch_bounds__(256) void k_scan_aw(const int* __restrict__ cnt, float* __restrict__ dinv,
                                                 int* __restrict__ rowptr, int* __restrict__ flags) {
  __shared__ int sd[256];
  __shared__ int s_prefix;
  int b = blockIdx.x;
  int base = b * 1024;
  int t = threadIdx.x;
  int v[4]; int s = 0;
  #pragma unroll
  for (int i = 0; i < 4; ++i) {
    int idx = base + t * 4 + i;
    if (idx < N_NODES) {
      int c = cnt[idx];
      v[i] = c;
      dinv[idx] = rsqrtf((float)(c + 1));
    } else v[i] = 0;
    s += v[i];
  }
  sd[t] = s; __syncthreads();
  for (int off = 1; off < 256; off <<= 1) {
    int y = (t >= off) ? sd[t - off] : 0;
    __syncthreads();
    sd[t] += y;
    __syncthreads();
  }
  int local_excl = sd[t] - s;
  int total = sd[255];
  if (t == 0) {
    atomicExch(&flags[8 + b], total);
    __threadfence();
    atomicAdd(&flags[0], 1);
    while (atomicAdd(&flags[0], 0) < NB_SCAN) { }
  }
  __syncthreads();
  // wave 0: parallel read of all partials; prefix = sum of partials with index < b
  if (t < 64) {
    int part = (t < NB_SCAN) ? atomicAdd(&flags[8 + t], 0) : 0;
    int pre = (t < b) ? part : 0;
    int tot = part;
    #pragma unroll
    for (int off = 32; off > 0; off >>= 1) {
      pre += __shfl_xor(pre, off, 64);
      tot += __shfl_xor(tot, off, 64);
    }
    if (t == 0) {
      s_prefix = pre;
      if (b == NB_SCAN - 1) rowptr[N_NODES] = tot;
    }
  }
  __syncthreads();
  int pre = s_prefix + local_excl;
  #pragma unroll
  for (int i = 0; i < 4; ++i) {
    int idx = base + t * 4 + i;
    if (idx < N_NODES) rowptr[idx] = pre;
    pre += v[i];
  }
}

// ---------------- megaB: CSR fill (no atomics, 4/thread)  ||  gemm1 ----------------

__global__ __launch_bounds__(256) void k_megaB(const int* __restrict__ src, const int* __restrict__ dst,
                                               const int* __restrict__ rowptr, const int* __restrict__ epos,
                                               int* __restrict__ esrc,
                                               const float* __restrict__ x,
                                               const unsigned short* __restrict__ W1th,
                                               const unsigned short* __restrict__ W1tl,
                                               unsigned short* __restrict__ hout) {
  int bid = blockIdx.x;
  union U { uint4 u; bf16x8 h; };
  if (bid < G_EDGE4) {
    int i0 = bid * 1024 + threadIdx.x * 4;
    if (i0 < N_EDGES) {
      int4 s4 = *(const int4*)(src + i0);
      int4 d4 = *(const int4*)(dst + i0);
      int4 e4 = *(const int4*)(epos + i0);
      esrc[rowptr[d4.x] + e4.x] = s4.x;
      esrc[rowptr[d4.y] + e4.y] = s4.y;
      esrc[rowptr[d4.z] + e4.z] = s4.z;
      esrc[rowptr[d4.w] + e4.w] = s4.w;
    }
  } else {
    // ---- node GEMM layer 1: hout = x @ W1 (hi/lo 3-term, bf16 out) ----
    int wave = threadIdx.x >> 6, lane = threadIdx.x & 63;
    int l15 = lane & 15, quad = lane >> 4;
    int r0 = (bid - G_EDGE4) * 128 + wave * 32;
    f32x4 acc[2][8];
    #pragma unroll
    for (int mt = 0; mt < 2; ++mt)
      #pragma unroll
      for (int nt = 0; nt < 8; ++nt) acc[mt][nt] = f32x4{0.f, 0.f, 0.f, 0.f};
    #pragma unroll
    for (int ks = 0; ks < 4; ++ks) {
      int k0 = ks * 32 + quad * 8;
      bf16x8 ah[2], al[2];
      #pragma unroll
      for (int mt = 0; mt < 2; ++mt) {
        int row = r0 + mt * 16 + l15;
        row = (row < N_NODES) ? row : (N_NODES - 1);
        const float* xp = x + (size_t)row * DIM + k0;
        float xv[8];
        *(float4*)(xv)     = *(const float4*)(xp);
        *(float4*)(xv + 4) = *(const float4*)(xp + 4);
        #pragma unroll
        for (int j = 0; j < 8; ++j) {
          unsigned short h = f2bf(xv[j]);
          ah[mt][j] = (short)h;
          al[mt][j] = (short)f2bf(xv[j] - bf2f(h));
        }
      }
      #pragma unroll
      for (int nt = 0; nt < 8; ++nt) {
        U bh, bl;
        bh.u = *(const uint4*)(W1th + (nt * 16 + l15) * DIM + k0);
        bl.u = *(const uint4*)(W1tl + (nt * 16 + l15) * DIM + k0);
        #pragma unroll
        for (int mt = 0; mt < 2; ++mt) {
          acc[mt][nt] = __builtin_amdgcn_mfma_f32_16x16x32_bf16(ah[mt], bh.h, acc[mt][nt], 0, 0, 0);
          acc[mt][nt] = __builtin_amdgcn_mfma_f32_16x16x32_bf16(al[mt], bh.h, acc[mt][nt], 0, 0, 0);
          acc[mt][nt] = __builtin_amdgcn_mfma_f32_16x16x32_bf16(ah[mt], bl.h, acc[mt][nt], 0, 0, 0);
        }
      }
    }
    #pragma unroll
    for (int mt = 0; mt < 2; ++mt)
      #pragma unroll
      for (int reg = 0; reg < 4; ++reg) {
        int row = r0 + mt * 16 + quad * 4 + reg;
        if (row < N_NODES) {
          #pragma unroll
          for (int nt = 0; nt < 8; ++nt)
            hout[(size_t)row * DIM + nt * 16 + l15] = f2bf(acc[mt][nt][reg]);
        }
      }
  }
}

// ---------------- agg: bf16 plane in -> hi/lo bf16 planes out ----------------

__global__ __launch_bounds__(256) void k_agg_hl(const unsigned short* __restrict__ h,
                                                const int* __restrict__ rowptr,
                                                const int* __restrict__ esrc, const float* __restrict__ dinv,
                                                const float* __restrict__ bias,
                                                unsigned short* __restrict__ outh,
                                                unsigned short* __restrict__ outl) {
  int node = blockIdx.x * 8 + (threadIdx.x >> 5);
  if (node >= N_NODES) return;
  int lane = threadIdx.x & 31;
  const ushort4* h4 = (const ushort4*)h;
  float di = dinv[node];
  ushort4 hv = h4[(size_t)node * 32 + lane];
  float ax = di * bf2f(hv.x), ay = di * bf2f(hv.y), az = di * bf2f(hv.z), aw = di * bf2f(hv.w);
  int e = rowptr[node], end = rowptr[node + 1];
  for (; e + 3 < end; e += 4) {
    int s0 = esrc[e], s1 = esrc[e + 1], s2 = esrc[e + 2], s3 = esrc[e + 3];
    float d0 = dinv[s0], d1 = dinv[s1], d2 = dinv[s2], d3 = dinv[s3];
    ushort4 v0 = h4[(size_t)s0 * 32 + lane];
    ushort4 v1 = h4[(size_t)s1 * 32 + lane];
    ushort4 v2 = h4[(size_t)s2 * 32 + lane];
    ushort4 v3 = h4[(size_t)s3 * 32 + lane];
    ax = fmaf(d0, bf2f(v0.x), ax); ay = fmaf(d0, bf2f(v0.y), ay); az = fmaf(d0, bf2f(v0.z), az); aw = fmaf(d0, bf2f(v0.w), aw);
    ax = fmaf(d1, bf2f(v1.x), ax); ay = fmaf(d1, bf2f(v1.y), ay); az = fmaf(d1, bf2f(v1.z), az); aw = fmaf(d1, bf2f(v1.w), aw);
    ax = fmaf(d2, bf2f(v2.x), ax); ay = fmaf(d2, bf2f(v2.y), ay); az = fmaf(d2, bf2f(v2.z), az); aw = fmaf(d2, bf2f(v2.w), aw);
    ax = fmaf(d3, bf2f(v3.x), ax); ay = fmaf(d3, bf2f(v3.y), ay); az = fmaf(d3, bf2f(v3.z), az); aw = fmaf(d3, bf2f(v3.w), aw);
  }
  for (; e < end; ++e) {
    int s = esrc[e];
    float ds = dinv[s];
    ushort4 vs = h4[(size_t)s * 32 + lane];
    ax = fmaf(ds, bf2f(vs.x), ax); ay = fmaf(ds, bf2f(vs.y), ay);
    az = fmaf(ds, bf2f(vs.z), az); aw = fmaf(ds, bf2f(vs.w), aw);
  }
  float4 bb = ((const float4*)bias)[lane];
  float vx = fmaf(di, ax, bb.x), vy = fmaf(di, ay, bb.y);
  float vz = fmaf(di, az, bb.z), vw = fmaf(di, aw, bb.w);
  ushort4 hi4, lo4;
  hi4.x = f2bf(vx); lo4.x = f2bf(vx - bf2f(hi4.x));
  hi4.y = f2bf(vy); lo4.y = f2bf(vy - bf2f(hi4.y));
  hi4.z = f2bf(vz); lo4.z = f2bf(vz - bf2f(hi4.z));
  hi4.w = f2bf(vw); lo4.w = f2bf(vw - bf2f(hi4.w));
  ((ushort4*)outh)[(size_t)node * 32 + lane] = hi4;
  ((ushort4*)outl)[(size_t)node * 32 + lane] = lo4;
}

// ---------------- gemm2: A from hi/lo planes, 3-term, bf16 out ----------------

__global__ __launch_bounds__(256) void k_gemm_hl(const unsigned short* __restrict__ xh,
                                                 const unsigned short* __restrict__ xl,
                                                 const unsigned short* __restrict__ Wth,
                                                 const unsigned short* __restrict__ Wtl,
                                                 unsigned short* __restrict__ out, int nrows) {
  int wave = threadIdx.x >> 6, lane = threadIdx.x & 63;
  int l15 = lane & 15, quad = lane >> 4;
  int r0 = blockIdx.x * 128 + wave * 32;
  f32x4 acc[2][8];
  #pragma unroll
  for (int mt = 0; mt < 2; ++mt)
    #pragma unroll
    for (int nt = 0; nt < 8; ++nt) acc[mt][nt] = f32x4{0.f, 0.f, 0.f, 0.f};
  union U { uint4 u; bf16x8 h; };
  #pragma unroll
  for (int ks = 0; ks < 4; ++ks) {
    int k0 = ks * 32 + quad * 8;
    U ah[2], al[2];
    #pragma unroll
    for (int mt = 0; mt < 2; ++mt) {
      int row = r0 + mt * 16 + l15;
      row = (row < nrows) ? row : (nrows - 1);
      ah[mt].u = *(const uint4*)(xh + (size_t)row * DIM + k0);
      al[mt].u = *(const uint4*)(xl + (size_t)row * DIM + k0);
    }
    #pragma unroll
    for (int nt = 0; nt < 8; ++nt) {
      U bh, bl;
      bh.u = *(const uint4*)(Wth + (nt * 16 + l15) * DIM + k0);
      bl.u = *(const uint4*)(Wtl + (nt * 16 + l15) * DIM + k0);
      #pragma unroll
      for (int mt = 0; mt < 2; ++mt) {
        acc[mt][nt] = __builtin_amdgcn_mfma_f32_16x16x32_bf16(ah[mt].h, bh.h, acc[mt][nt], 0, 0, 0);
        acc[mt][nt] = __builtin_amdgcn_mfma_f32_16x16x32_bf16(al[mt].h, bh.h, acc[mt][nt], 0, 0, 0);
        acc[mt][nt] = __builtin_amdgcn_mfma_f32_16x16x32_bf16(ah[mt].h, bl.h, acc[mt][nt], 0, 0, 0);
      }
    }
  }
  #pragma unroll
  for (int mt = 0; mt < 2; ++mt)
    #pragma unroll
    for (int reg = 0; reg < 4; ++reg) {
      int row = r0 + mt * 16 + quad * 4 + reg;
      if (row < nrows) {
        #pragma unroll
        for (int nt = 0; nt < 8; ++nt)
          out[(size_t)row * DIM + nt * 16 + l15] = f2bf(acc[mt][nt][reg]);
      }
    }
}

// ---------------- predict via MFMA: 4 batch-tiles per Q-load ----------------

__global__ __launch_bounds__(256) void k_predict_mfma(const unsigned short* __restrict__ xh,
                                                      const unsigned short* __restrict__ xl,
                                                      const int* __restrict__ head,
                                                      const int* __restrict__ tail,
                                                      const unsigned short* __restrict__ Qbf,
                                                      float* __restrict__ out) {
  __shared__ __align__(16) unsigned short Qs[DIM * QPAD];
  __shared__ int Hidx[128];
  __shared__ int Tidx[128];
  int r = blockIdx.y;
  const unsigned short* Qr = Qbf + (size_t)r * DIM * DIM;
  for (int i = threadIdx.x; i < DIM * DIM / 8; i += 256) {
    int d = i >> 4, c = (i & 15) * 8;
    uint4 v = ((const uint4*)Qr)[i];
    *(uint4*)(&Qs[d * QPAD + c]) = v;
  }
  int wave = threadIdx.x >> 6, lane = threadIdx.x & 63;
  int l15 = lane & 15, quad = lane >> 4;
  union U { uint4 u; bf16x8 h; };

  for (int k = 0; k < 4; ++k) {
    int tile = blockIdx.x * 4 + k;
    __syncthreads();  // protect Hidx/Tidx (and on k==0, Qs) from previous readers
    if (threadIdx.x < 128) Hidx[threadIdx.x] = head[tile * 128 + threadIdx.x];
    else Tidx[threadIdx.x - 128] = tail[tile * 128 + threadIdx.x - 128];
    __syncthreads();
    int t0r = Tidx[wave * 32 + l15];
    int t1r = Tidx[wave * 32 + 16 + l15];

    f32x4 acc[2][8];
    #pragma unroll
    for (int m = 0; m < 2; ++m)
      #pragma unroll
      for (int n = 0; n < 8; ++n) acc[m][n] = f32x4{0.f, 0.f, 0.f, 0.f};

    #pragma unroll
    for (int ks = 0; ks < 4; ++ks) {
      int eoff = ks * 32 + quad * 8;
      U a0, a1;
      a0.u = *(const uint4*)(xh + (size_t)t0r * DIM + eoff);   // tail = hi plane
      a1.u = *(const uint4*)(xh + (size_t)t1r * DIM + eoff);
      #pragma unroll
      for (int nt = 0; nt < 8; ++nt) {
        U b; b.u = *(const uint4*)(&Qs[(nt * 16 + l15) * QPAD + eoff]);
        acc[0][nt] = __builtin_amdgcn_mfma_f32_16x16x32_bf16(a0.h, b.h, acc[0][nt], 0, 0, 0);
        acc[1][nt] = __builtin_amdgcn_mfma_f32_16x16x32_bf16(a1.h, b.h, acc[1][nt], 0, 0, 0);
      }
    }

    int bbase = tile * 128 + wave * 32;
    #pragma unroll
    for (int m = 0; m < 2; ++m) {
      #pragma unroll
      for (int reg = 0; reg < 4; ++reg) {
        int bl = wave * 32 + m * 16 + quad * 4 + reg;
        int hrow = Hidx[bl];
        float s = 0.f;
        #pragma unroll
        for (int nt = 0; nt < 8; ++nt) {
          size_t idx = (size_t)hrow * DIM + nt * 16 + l15;
          s += (bf2f(xh[idx]) + bf2f(xl[idx])) * acc[m][nt][reg];  // head = hi+lo
        }
        #pragma unroll
        for (int off = 1; off < 16; off <<= 1) s += __shfl_xor(s, off, 64);
        if (l15 == 0) out[(size_t)(bbase + m * 16 + quad * 4 + reg) * N_REL + r] = s;
      }
    }
  }
}

// ---------------- launch ----------------

extern "C" void kernel_launch(void* const* d_in, const int* in_sizes, int n_in,
                              void* d_out, int out_size, void* d_ws, size_t ws_size,
                              hipStream_t stream) {
  (void)in_sizes; (void)n_in; (void)out_size; (void)ws_size;
  const float* init_emb = (const float*)d_in[0];
  const float* W1  = (const float*)d_in[1];
  const float* b1  = (const float*)d_in[2];
  const float* W2  = (const float*)d_in[3];
  const float* b2  = (const float*)d_in[4];
  const float* Rel = (const float*)d_in[5];
  const float* M   = (const float*)d_in[6];
  const int* head  = (const int*)d_in[7];
  const int* tail  = (const int*)d_in[8];
  const int* src   = (const int*)d_in[9];
  const int* dst   = src + N_EDGES;
  float* out = (float*)d_out;

  char* p = (char*)d_ws;
  auto alloc = [&](size_t bytes) { char* q = p; p += (bytes + 511) & ~(size_t)511; return q; };
  int*   cnt    = (int*)alloc((size_t)N_NODES * 4);
  int*   rowptr = (int*)alloc((size_t)(N_NODES + 1) * 4);
  int*   flags  = (int*)alloc(64 * 4);
  int*   esrc   = (int*)alloc((size_t)N_EDGES * 4);
  int*   epos   = (int*)alloc((size_t)N_EDGES * 4);
  float* dinv   = (float*)alloc((size_t)N_NODES * 4);
  unsigned short* hbuf1 = (unsigned short*)alloc((size_t)N_NODES * DIM * 2);
  unsigned short* aggh  = (unsigned short*)alloc((size_t)N_NODES * DIM * 2);
  unsigned short* aggl  = (unsigned short*)alloc((size_t)N_NODES * DIM * 2);
  unsigned short* hbuf2 = (unsigned short*)alloc((size_t)N_NODES * DIM * 2);
  unsigned short* xh    = (unsigned short*)alloc((size_t)N_NODES * DIM * 2);
  unsigned short* xl    = (unsigned short*)alloc((size_t)N_NODES * DIM * 2);
  unsigned short* Qbf   = (unsigned short*)alloc((size_t)N_REL * DIM * DIM * 2);
  unsigned short* W1th  = (unsigned short*)alloc((size_t)DIM * DIM * 2);
  unsigned short* W1tl  = (unsigned short*)alloc((size_t)DIM * DIM * 2);
  unsigned short* W2th  = (unsigned short*)alloc((size_t)DIM * DIM * 2);
  unsigned short* W2tl  = (unsigned short*)alloc((size_t)DIM * DIM * 2);
  unsigned short* Mth   = (unsigned short*)alloc((size_t)DIM * DIM * 2);

  // 1: zero cnt/flags + weight prep
  k_prep_zero<<<256, 256, 0, stream>>>(W1, W2, M, W1th, W1tl, W2th, W2tl, Mth, cnt, flags);
  // 2: count(+epos, 4/thr) || decoder TQ
  k_megaA<<<G_EDGE4 + G_TQ, 256, 0, stream>>>(dst, cnt, epos, Rel, Mth, Qbf);
  // 3: single-dispatch all-wait scan (dinv + rowptr)
  k_scan_aw<<<NB_SCAN, 256, 0, stream>>>(cnt, dinv, rowptr, flags);
  // 4: fill (no atomics, 4/thr) || gemm1
  k_megaB<<<G_EDGE4 + G_GEMM, 256, 0, stream>>>(src, dst, rowptr, epos, esrc,
                                                init_emb, W1th, W1tl, hbuf1);
  // 5: agg1 -> hi/lo planes
  k_agg_hl<<<(N_NODES + 7) / 8, 256, 0, stream>>>(hbuf1, rowptr, esrc, dinv, b1, aggh, aggl);
  // 6: gemm2 from planes
  k_gemm_hl<<<(N_NODES + 127) / 128, 256, 0, stream>>>(aggh, aggl, W2th, W2tl, hbuf2, N_NODES);
  // 7: agg2 -> hi/lo planes
  k_agg_hl<<<(N_NODES + 7) / 8, 256, 0, stream>>>(hbuf2, rowptr, esrc, dinv, b2, xh, xl);
  // 8: predict (4 tiles per Q-load)
  k_predict_mfma<<<dim3(4, N_REL), 256, 0, stream>>>(xh, xl, head, tail, Qbf, out);
}